// Round 1
// baseline (88.508 us; speedup 1.0000x reference)
//
#include <hip/hip_runtime.h>

// RoiPoolingConv: crop_and_resize (bilinear, 14x14 grid) + 2x2 max pool
// fm: (38,50,512) f32; rois: (512,5) f32 [batch, x1, y1, x2, y2]
// out[n,ph,pw,c] = max over (jy,ix in {0,1}) of bilinear sample (2ph+jy, 2pw+ix)
//
// R7: one block per (n, ph) instead of (n, ph, pw). The 14 x-samples are
// walked with a fully-unrolled register sliding window (pv0/pv1 = previous
// column pair per row), so columns shared between consecutive samples are
// loaded once instead of once per pw-block. y-rows deduped via NR template
// (2/3/4 distinct rows); ROI decode + y setup amortized over all 7 pw.
// All pv/d indices are compile-time (template NR + full unroll) -> registers.

#define FM_H 38
#define FM_W 50
#define NCH  512

typedef float v4f __attribute__((ext_vector_type(4)));

__device__ __forceinline__ float4 lerp4(const float4 a, const float4 b, const float w) {
    const float iw = 1.0f - w;
    return make_float4(a.x * iw + b.x * w,
                       a.y * iw + b.y * w,
                       a.z * iw + b.z * w,
                       a.w * iw + b.w * w);
}

__device__ __forceinline__ float4 max4(const float4 a, const float4 b) {
    return make_float4(fmaxf(a.x, b.x), fmaxf(a.y, b.y),
                       fmaxf(a.z, b.z), fmaxf(a.w, b.w));
}

#define LD4(p) (*(const float4*)(p))

__device__ __forceinline__ void st_nt4(float* p, const float4 v) {
    v4f vv;
    vv.x = v.x; vv.y = v.y; vv.z = v.z; vv.w = v.w;
    __builtin_nontemporal_store(vv, (v4f*)p);
}

// NR = number of distinct fm rows (2: ycs==0, 3: ycs==1, 4: ycs==2).
// s0 (weight wy0) uses rows d[0],d[1]; s1 (weight wy1) uses d[NR-2],d[NR-1].
template<int NR>
__device__ __forceinline__ void roi_rows(const float* rp0, const float* rp1,
                                         const float* rp2, const float* rp3,
                                         const float wy0, const float wy1,
                                         const float x1, const float dx,
                                         float* __restrict__ outp)
{
    const float SX = 49.0f / 800.0f;    // (W-1)/IM_W
    const float* rp[4] = {rp0, rp1, rp2, rp3};

    int pa = 0;                 // cached column pair: (pa, min(pa+1,49))
    float4 pv0[NR], pv1[NR];    // values at those columns, per distinct row
    float4 cur;

    #pragma unroll
    for (int i = 0; i < 14; ++i) {
        const float t  = (float)i * (1.0f / 13.0f);
        const float xx = (x1 + t * dx) * SX;
        const float xf = floorf(xx);
        const float wx = xx - xf;          // weight from UNclipped floor
        int a = (int)xf; a = min(max(a, 0), FM_W - 1);
        const int b    = min(a + 1, FM_W - 1);
        const int offA = a * NCH;
        const int offB = b * NCH;

        if (i == 0) {                       // compile-time branch
            #pragma unroll
            for (int r = 0; r < NR; ++r) {
                pv0[r] = LD4(rp[r] + offA);
                pv1[r] = LD4(rp[r] + offB);
            }
            pa = a;
        } else if (a != pa) {               // block-uniform branch
            if (a == pa + 1) {
                // shift: old right column becomes new left column
                #pragma unroll
                for (int r = 0; r < NR; ++r) {
                    pv0[r] = pv1[r];
                    pv1[r] = LD4(rp[r] + offB);
                }
            } else {
                #pragma unroll
                for (int r = 0; r < NR; ++r) {
                    pv0[r] = LD4(rp[r] + offA);
                    pv1[r] = LD4(rp[r] + offB);
                }
            }
            pa = a;
        }

        // x-interp per distinct row, then y-interp for the two y-samples
        float4 d[NR];
        #pragma unroll
        for (int r = 0; r < NR; ++r) d[r] = lerp4(pv0[r], pv1[r], wx);
        const float4 s0 = lerp4(d[0],      d[1],      wy0);
        const float4 s1 = lerp4(d[NR - 2], d[NR - 1], wy1);
        const float4 s  = max4(s0, s1);

        if ((i & 1) == 0) {
            cur = s;
        } else {
            cur = max4(cur, s);
            st_nt4(outp + (i >> 1) * NCH, cur);   // out[n,ph,pw= i>>1, c..c+3]
        }
    }
}

__global__ __launch_bounds__(128) void roi_pool_kernel(
    const float* __restrict__ fm,
    const float* __restrict__ rois,
    float* __restrict__ out)
{
    const int bi = blockIdx.x;          // n*7 + ph
    const int n  = bi / 7;
    const int ph = bi - n * 7;
    const int c  = threadIdx.x * 4;     // 4 channels per thread (float4)

    // ROI box (block-uniform)
    const float x1 = rois[n * 5 + 1];
    const float y1 = rois[n * 5 + 2];
    const float x2 = rois[n * 5 + 3];
    const float y2 = rois[n * 5 + 4];
    const float SY = 37.0f / 600.0f;    // (H-1)/IM_H
    const float dx = x2 - x1;
    const float dy = y2 - y1;

    // y samples: j = 2*ph + {0,1}
    const float t0  = (float)(2 * ph)     * (1.0f / 13.0f);
    const float t1  = (float)(2 * ph + 1) * (1.0f / 13.0f);
    const float yy0 = (y1 + t0 * dy) * SY;
    const float yy1 = (y1 + t1 * dy) * SY;
    const float yf0 = floorf(yy0), yf1 = floorf(yy1);
    int a0 = (int)yf0; a0 = min(max(a0, 0), FM_H - 1);
    int a1 = (int)yf1; a1 = min(max(a1, 0), FM_H - 1);
    const int yA0 = a0, yB0 = min(a0 + 1, FM_H - 1);
    const int yA1 = a1, yB1 = min(a1 + 1, FM_H - 1);
    const float wy0 = yy0 - yf0;
    const float wy1 = yy1 - yf1;

    const float* fmc = fm + c;
    const float* rA0 = fmc + (size_t)yA0 * (FM_W * NCH);
    const float* rB0 = fmc + (size_t)yB0 * (FM_W * NCH);
    const float* rA1 = fmc + (size_t)yA1 * (FM_W * NCH);
    const float* rB1 = fmc + (size_t)yB1 * (FM_W * NCH);

    // out[n, ph, pw, c] ; bi*7*NCH == (n*49 + ph*7)*NCH
    float* outp = out + (size_t)bi * (7 * NCH) + c;

    // 0 = same cell (rows {A0,B0}), 1 = adjacent (share B0==A1), 2 = disjoint
    const int ycs = (yA1 == yA0) ? 0 : ((yA1 == yB0) ? 1 : 2);
    if (ycs == 0)      roi_rows<2>(rA0, rB0, rB0, rB0, wy0, wy1, x1, dx, outp);
    else if (ycs == 1) roi_rows<3>(rA0, rB0, rB1, rB1, wy0, wy1, x1, dx, outp);
    else               roi_rows<4>(rA0, rB0, rA1, rB1, wy0, wy1, x1, dx, outp);
}

extern "C" void kernel_launch(void* const* d_in, const int* in_sizes, int n_in,
                              void* d_out, int out_size, void* d_ws, size_t ws_size,
                              hipStream_t stream) {
    const float* fm   = (const float*)d_in[0];   // (1,38,50,512) f32
    const float* rois = (const float*)d_in[1];   // (512,5) f32
    float* out = (float*)d_out;                  // (1,512,7,7,512) f32

    const int N = in_sizes[1] / 5;               // 512 rois
    const int blocks = N * 7;                    // one block per (roi, ph)
    roi_pool_kernel<<<blocks, NCH / 4, 0, stream>>>(fm, rois, out);
}